// Round 7
// baseline (208.849 us; speedup 1.0000x reference)
//
#include <hip/hip_runtime.h>

#define B_ 64
#define C_ 3
#define H_ 384
#define W_ 384
#define HW_ (H_ * W_)

typedef float f32x2 __attribute__((ext_vector_type(2)));
typedef f32x2 __attribute__((aligned(4))) f32x2_u;

// R4 structure (the measured local optimum: 1 px/thread, 6 pair-gathers,
// 16 VGPR, 24 waves/CU) + block-uniform INTERIOR fast path that strips all
// boundary VALU (8 cmp + 6 logic + 10 clamp + 12 cndmask per px) for the
// ~80% of 128x2 tiles whose whole tap region is provably inside the image.
__global__ __launch_bounds__(256) void affine_sample_kernel(
    const float* __restrict__ imgs,
    const float* __restrict__ theta,
    float* __restrict__ out)
{
    // XCD swizzle: 36,864 blocks / 8 XCDs = 4,608 per XCD = 8 whole images.
    int nb = gridDim.x;
    int bid = blockIdx.x;
    int sb = (bid & 7) * (nb >> 3) + (bid >> 3);

    // 128x2 tile per block (R3/R4 mapping).
    int b   = sb / 576;
    int rem = sb - b * 576;
    int rp  = rem / 3;                     // row-pair index
    int xt  = rem - rp * 3;                // x-tile index
    b = __builtin_amdgcn_readfirstlane(b);

    int tid = threadIdx.x;
    int x = xt * 128 + (tid & 127);        // wave0/1: row y, wave2/3: row y+1
    int y = rp * 2 + (tid >> 7);

    const float* th = theta + b * 6;
    float t00 = th[0], t01 = th[1], t02 = th[2];
    float t10 = th[3], t11 = th[4], t12 = th[5];

    // ---- block-uniform interior test from the 4 tile corners ----
    float xgl = (float)(xt * 128) - 191.5f;
    float xgr = xgl + 127.0f;
    float ygt = (float)(rp * 2) - 191.5f;
    float ygb = ygt + 1.0f;

    float ix00 = fmaf(xgl, t00, fmaf(ygt, t01, t02)) + 191.5f;
    float ix10 = fmaf(xgr, t00, fmaf(ygt, t01, t02)) + 191.5f;
    float ix01 = fmaf(xgl, t00, fmaf(ygb, t01, t02)) + 191.5f;
    float ix11 = fmaf(xgr, t00, fmaf(ygb, t01, t02)) + 191.5f;
    float iy00 = fmaf(xgl, t10, fmaf(ygt, t11, t12)) + 191.5f;
    float iy10 = fmaf(xgr, t10, fmaf(ygt, t11, t12)) + 191.5f;
    float iy01 = fmaf(xgl, t10, fmaf(ygb, t11, t12)) + 191.5f;
    float iy11 = fmaf(xgr, t10, fmaf(ygb, t11, t12)) + 191.5f;

    float ixmin = fminf(fminf(ix00, ix10), fminf(ix01, ix11));
    float ixmax = fmaxf(fmaxf(ix00, ix10), fmaxf(ix01, ix11));
    float iymin = fminf(fminf(iy00, iy10), fminf(iy01, iy11));
    float iymax = fmaxf(fmaxf(iy00, iy10), fmaxf(iy01, iy11));

    // Interior iff every pixel has floor(ix) in [0, W-2] and floor(iy) in
    // [0, H-2]: ix,iy in [0, W-1). Margin 0.02 >> fma rounding (<1e-4 here);
    // affine extrema are attained at corners in exact arithmetic.
    int interior_i = (ixmin >= 0.02f) & (ixmax <= (float)(W_ - 1) - 0.02f) &
                     (iymin >= 0.02f) & (iymax <= (float)(H_ - 1) - 0.02f);
    interior_i = __builtin_amdgcn_readfirstlane(interior_i);  // scalar branch

    float xg = (float)x - 191.5f;
    float yg = (float)y - 191.5f;

    float ix = fmaf(xg, t00, fmaf(yg, t01, t02)) + 191.5f;
    float iy = fmaf(xg, t10, fmaf(yg, t11, t12)) + 191.5f;

    float x0f = floorf(ix);
    float y0f = floorf(iy);
    float wx1 = ix - x0f;
    float wy1 = iy - y0f;
    float wx0 = 1.0f - wx1;
    float wy0 = 1.0f - wy1;

    const float* bimg = imgs + (size_t)b * (C_ * HW_);
    float* bout = out + (size_t)b * (C_ * HW_) + y * W_ + x;

    if (interior_i) {
        // ---- interior: no clamps, no valid-masks, no selects ----
        // Bit-identical to the R4 path here: selx0/selx1 would be T/F and all
        // valid flags 1.0, so v00..v11 == vt.x, vt.y, vb.x, vb.y exactly.
        int xb = (int)x0f;                 // x0f in [0,382], exact cast
        int y0 = (int)y0f;
        float w00 = wx0 * wy0;
        float w01 = wx1 * wy0;
        float w10 = wx0 * wy1;
        float w11 = wx1 * wy1;
        int oT = y0 * W_ + xb;
        int oB = oT + W_;

        f32x2 vt[C_], vb[C_];
#pragma unroll
        for (int c = 0; c < C_; ++c) {     // all 6 gathers issued up front
            const float* p = bimg + c * HW_;
            vt[c] = *reinterpret_cast<const f32x2_u*>(p + oT);
            vb[c] = *reinterpret_cast<const f32x2_u*>(p + oB);
        }
#pragma unroll
        for (int c = 0; c < C_; ++c) {
            float r = fmaf(vt[c].x, w00, fmaf(vt[c].y, w01,
                      fmaf(vb[c].x, w10, vb[c].y * w11)));
            bout[c * HW_] = r;
        }
    } else {
        // ---- boundary: exact R4 path (clamps + masks + pair selects) ----
        float x1f = x0f + 1.0f;
        float y1f = y0f + 1.0f;

        bool vx0 = (x0f >= 0.0f) && (x0f < (float)W_);
        bool vx1 = (x1f >= 0.0f) && (x1f < (float)W_);
        bool vy0 = (y0f >= 0.0f) && (y0f < (float)H_);
        bool vy1 = (y1f >= 0.0f) && (y1f < (float)H_);

        int x0 = (int)fminf(fmaxf(x0f, 0.0f), (float)(W_ - 1));
        int x1 = (int)fminf(fmaxf(x1f, 0.0f), (float)(W_ - 1));
        int y0 = (int)fminf(fmaxf(y0f, 0.0f), (float)(H_ - 1));
        int y1 = (int)fminf(fmaxf(y1f, 0.0f), (float)(H_ - 1));
        int xb = (int)fminf(fmaxf(x0f, 0.0f), (float)(W_ - 2));

        bool selx0 = (x0 == xb);
        bool selx1 = (x1 == xb);

        float w00 = wx0 * wy0 * ((vx0 && vy0) ? 1.0f : 0.0f);
        float w01 = wx1 * wy0 * ((vx1 && vy0) ? 1.0f : 0.0f);
        float w10 = wx0 * wy1 * ((vx0 && vy1) ? 1.0f : 0.0f);
        float w11 = wx1 * wy1 * ((vx1 && vy1) ? 1.0f : 0.0f);

        int oT = y0 * W_ + xb;
        int oB = y1 * W_ + xb;

        f32x2 vt[C_], vb[C_];
#pragma unroll
        for (int c = 0; c < C_; ++c) {
            const float* p = bimg + c * HW_;
            vt[c] = *reinterpret_cast<const f32x2_u*>(p + oT);
            vb[c] = *reinterpret_cast<const f32x2_u*>(p + oB);
        }
#pragma unroll
        for (int c = 0; c < C_; ++c) {
            float v00 = selx0 ? vt[c].x : vt[c].y;
            float v01 = selx1 ? vt[c].x : vt[c].y;
            float v10 = selx0 ? vb[c].x : vb[c].y;
            float v11 = selx1 ? vb[c].x : vb[c].y;
            float r = fmaf(v00, w00, fmaf(v01, w01,
                      fmaf(v10, w10, v11 * w11)));
            bout[c * HW_] = r;
        }
    }
}

extern "C" void kernel_launch(void* const* d_in, const int* in_sizes, int n_in,
                              void* d_out, int out_size, void* d_ws, size_t ws_size,
                              hipStream_t stream) {
    const float* imgs = (const float*)d_in[0];
    const float* theta = (const float*)d_in[1];
    float* out = (float*)d_out;
    int total = B_ * H_ * W_;                 // 9,437,184
    affine_sample_kernel<<<total / 256, 256, 0, stream>>>(imgs, theta, out);
}